// Round 13
// baseline (258.951 us; speedup 1.0000x reference)
//
#include <hip/hip_runtime.h>
#include <hip/hip_fp16.h>

#define N_NODES 50000
#define N_EDGES 1250000
#define HDIM    64
#define NGRAPH  64
#define NPART   400                        // partitions for CSR build
#define PSIZE   125                        // nodes per partition (400*125 = 50000 exact)
#define CAP     4096                       // bucket capacity per partition (mean 3125+375 pad, sigma 56)
#define SENTINEL N_NODES                   // dummy src row (zeroed) for 4-padding

struct alignas(8) h4 { __half2 a, b; };    // 4 fp16 features, one 8-byte load/store
struct alignas(16) h8 { __half2 a, b, c, d; };  // 8 fp16 features, one 16-byte LDS read

// fp16 dot2 with fp32 accumulate: v_dot2_f32_f16 if available, else unpack+fma
typedef _Float16 half2v __attribute__((ext_vector_type(2)));
#if __has_builtin(__builtin_amdgcn_fdot2)
__device__ inline float dot2acc(__half2 a, __half2 b, float c) {
    return __builtin_amdgcn_fdot2(__builtin_bit_cast(half2v, a),
                                  __builtin_bit_cast(half2v, b), c, false);
}
#else
__device__ inline float dot2acc(__half2 a, __half2 b, float c) {
    float2 fa = __half22float2(a), fb = __half22float2(b);
    return c + fa.x * fb.x + fa.y * fb.y;
}
#endif

// ---------------------------------------------------------------- bucket edges by partition
// fixed-capacity slots: partition p owns bucket[p*CAP .. p*CAP+CAP).
// packed entry: (src << 8) | (dst % PSIZE); src < 65536, dstLocal < 125.
__global__ void bucket_kernel(const int* __restrict__ ei, int* __restrict__ pcount,
                              int* __restrict__ bucket) {
    __shared__ int hist[NPART];
    __shared__ int sbase[NPART];
    int tid = threadIdx.x;
    for (int i = tid; i < NPART; i += 256) hist[i] = 0;
    __syncthreads();
    int chunk = (N_EDGES + gridDim.x - 1) / gridDim.x;
    int beg = blockIdx.x * chunk;
    int end = min(beg + chunk, N_EDGES);
    // phase 1: count this block's edges per partition
    for (int e = beg + tid; e < end; e += 256)
        atomicAdd(&hist[ei[N_EDGES + e] / PSIZE], 1);
    __syncthreads();
    // phase 2: reserve contiguous ranges in each partition's fixed slot
    for (int i = tid; i < NPART; i += 256) {
        sbase[i] = hist[i] ? atomicAdd(&pcount[i], hist[i]) : 0;
        hist[i] = 0;   // reuse as local offset
    }
    __syncthreads();
    // phase 3: scatter packed edges
    for (int e = beg + tid; e < end; e += 256) {
        int dst = ei[N_EDGES + e];
        int src = ei[e];
        int p = dst / PSIZE;
        int l = atomicAdd(&hist[p], 1);
        bucket[p * CAP + sbase[p] + l] = (src << 8) | (dst - p * PSIZE);
    }
}

// ---------------------------------------------------------------- per-partition deg+scan+row ranges+dinv+fill
// row ranges padded to multiples of 4; pad slots filled with SENTINEL src.
__global__ void csr_kernel(const int* __restrict__ pcount, const int* __restrict__ bucket,
                           int* __restrict__ row_beg, int* __restrict__ row_end,
                           float* __restrict__ dinv, int* __restrict__ csr_src) {
    __shared__ int hist[256];
    __shared__ int s[256];
    __shared__ int cur[128];
    int p = blockIdx.x;
    int tid = threadIdx.x;
    int base = p * CAP;
    int cnt = min(pcount[p], CAP);
    hist[tid] = 0;
    __syncthreads();
    // phase 1: degree histogram of this partition
    for (int e = tid; e < cnt; e += 256)
        atomicAdd(&hist[bucket[base + e] & 0xFF], 1);
    __syncthreads();
    int v  = (tid < PSIZE) ? hist[tid] : 0;
    int vp = (v + 3) & ~3;                  // padded degree (multiple of 4)
    s[tid] = vp;
    __syncthreads();
    // phase 2: in-LDS exclusive scan over padded degrees
    for (int off = 1; off < 256; off <<= 1) {
        int t = (tid >= off) ? s[tid - off] : 0;
        __syncthreads();
        s[tid] += t;
        __syncthreads();
    }
    int ex = s[tid] - vp;                   // 4-aligned exclusive prefix
    if (tid < PSIZE) {
        int node = p * PSIZE + tid;
        row_beg[node] = base + ex;
        row_end[node] = base + ex + vp;     // padded end
        dinv[node] = rsqrtf((float)v + 1.0f);   // +1 self-loop (real degree)
        cur[tid] = ex;
    }
    __syncthreads();
    // phase 3: fill csr_src (partition-local LDS cursors, no global atomics)
    for (int e = tid; e < cnt; e += 256) {
        int pk = bucket[base + e];
        int l = atomicAdd(&cur[pk & 0xFF], 1);
        csr_src[base + l] = pk >> 8;
    }
    __syncthreads();
    // phase 4: sentinel-fill the pad slots
    if (tid < PSIZE) {
        for (int q = ex + v; q < ex + vp; ++q)
            csr_src[base + q] = SENTINEL;
    }
}

// ---------------------------------------------------------------- GEMM 64x64 -> fp16, row-scaled by dinv
// xws[n][j] = dinv[n] * sum_k h[n][k] * W[k][j];  fp16 LDS tile + dot2 inner loop.
// W held per-lane as 32 half2 registers (loaded straight from L2; no W LDS stage).
__device__ inline __half2 stage2(const float* p, int i) {
    float2 v = ((const float2*)p)[i];
    return __floats2half2_rn(v.x, v.y);
}
__device__ inline __half2 stage2(const __half* p, int i) {
    return ((const __half2*)p)[i];
}

template <typename T>
__global__ void gemm64_kernel(const T* __restrict__ h, const float* __restrict__ W,
                              const float* __restrict__ dinv, __half* __restrict__ out) {
    __shared__ alignas(16) __half2 hs2[256];   // 8 rows x 32 half2 (fp16 tile)
    int tid = threadIdx.x;
    int tx = tid & 63;       // output column (lane)
    int r0 = (tid >> 6) * 2; // this wave's two rows within the 8-row chunk
    __half2 wcol2[32];       // W[:, tx] as fp16 pairs
#pragma unroll
    for (int k2 = 0; k2 < 32; ++k2)
        wcol2[k2] = __floats2half2_rn(W[(2 * k2) * 64 + tx], W[(2 * k2 + 1) * 64 + tx]);
    const int nchunks = N_NODES / 8;  // 6250, exact
    for (int grp = blockIdx.x; grp < nchunks; grp += gridDim.x) {
        __syncthreads();                       // protect hs2 from previous iter
        hs2[tid] = stage2(h + grp * 512, tid); // 8 rows of h -> fp16 LDS
        __syncthreads();
        float acc0 = 0.f, acc1 = 0.f;
        const h8* row0 = (const h8*)&hs2[r0 * 32];
        const h8* row1 = (const h8*)&hs2[(r0 + 1) * 32];
#pragma unroll
        for (int j = 0; j < 8; ++j) {          // 8 features per b128 LDS read
            h8 v0 = row0[j];
            h8 v1 = row1[j];
            acc0 = dot2acc(v0.a, wcol2[4 * j + 0], acc0);
            acc0 = dot2acc(v0.b, wcol2[4 * j + 1], acc0);
            acc0 = dot2acc(v0.c, wcol2[4 * j + 2], acc0);
            acc0 = dot2acc(v0.d, wcol2[4 * j + 3], acc0);
            acc1 = dot2acc(v1.a, wcol2[4 * j + 0], acc1);
            acc1 = dot2acc(v1.b, wcol2[4 * j + 1], acc1);
            acc1 = dot2acc(v1.c, wcol2[4 * j + 2], acc1);
            acc1 = dot2acc(v1.d, wcol2[4 * j + 3], acc1);
        }
        int nbase = grp * 8 + r0;
        out[nbase * 64 + tx]       = __float2half(acc0 * dinv[nbase]);
        out[(nbase + 1) * 64 + tx] = __float2half(acc1 * dinv[nbase + 1]);
    }
}

// ---------------------------------------------------------------- fused gather (one 16-lane group per node)
// padded rows: no tail loop; 4 edge indices per int4 load; pairwise fp16 adds.
// out[n] = fp16( dinv[n] * (sum_e xws[src_e] + xws[n]) + b );  relu opt.
__global__ void gather_g16_kernel(const int* __restrict__ row_beg, const int* __restrict__ row_end,
                                  const int* __restrict__ csr_src,
                                  const float* __restrict__ dinv, const __half* __restrict__ xws,
                                  const float* __restrict__ b, __half* __restrict__ out,
                                  int do_relu) {
    int tid = blockIdx.x * blockDim.x + threadIdx.x;
    int node = tid >> 4;         // one 16-lane group per node
    if (node >= N_NODES) return;
    int l4 = tid & 15;           // feature quad: features 4*l4 .. 4*l4+3
    int beg = row_beg[node];
    int endp = row_end[node];    // padded to multiple of 4
    float ax = 0.f, ay = 0.f, az = 0.f, aw = 0.f;
    for (int e = beg; e < endp; e += 4) {
        int4 sv = *(const int4*)(csr_src + e);   // 4 indices, one dwordx4 (4-aligned)
        h4 v0 = *(const h4*)(xws + sv.x * 64 + 4 * l4);
        h4 v1 = *(const h4*)(xws + sv.y * 64 + 4 * l4);
        h4 v2 = *(const h4*)(xws + sv.z * 64 + 4 * l4);
        h4 v3 = *(const h4*)(xws + sv.w * 64 + 4 * l4);
        __half2 pa0 = __hadd2(v0.a, v1.a), pb0 = __hadd2(v0.b, v1.b);  // pairwise fp16
        __half2 pa1 = __hadd2(v2.a, v3.a), pb1 = __hadd2(v2.b, v3.b);
        float2 fa0 = __half22float2(pa0), fb0 = __half22float2(pb0);
        float2 fa1 = __half22float2(pa1), fb1 = __half22float2(pb1);
        ax += fa0.x + fa1.x;  ay += fa0.y + fa1.y;
        az += fb0.x + fb1.x;  aw += fb0.y + fb1.y;
    }
    // epilogue (once per node, no shuffles needed)
    float d = dinv[node];
    h4 sv2 = *(const h4*)(xws + node * 64 + 4 * l4);
    float2 sa = __half22float2(sv2.a), sb = __half22float2(sv2.b);
    const float4 bb = *(const float4*)(b + 4 * l4);
    float vx = d * (ax + sa.x) + bb.x;
    float vy = d * (ay + sa.y) + bb.y;
    float vz = d * (az + sb.x) + bb.z;
    float vw = d * (aw + sb.y) + bb.w;
    if (do_relu) {
        vx = fmaxf(vx, 0.f); vy = fmaxf(vy, 0.f);
        vz = fmaxf(vz, 0.f); vw = fmaxf(vw, 0.f);
    }
    h4 o;
    o.a = __float22half2_rn(make_float2(vx, vy));
    o.b = __float22half2_rn(make_float2(vz, vw));
    *(h4*)(out + node * 64 + 4 * l4) = o;
}

// ---------------------------------------------------------------- fused pooling + head
// grid must be exactly 500 blocks (500*4 waves * 25 nodes = 50000, no idle waves).
// Last block (done-counter) computes the head via coherent atomic reads.
__global__ void poolhead_kernel(const __half* __restrict__ h, const int* __restrict__ batch,
                                float* __restrict__ pool, float* __restrict__ cnt,
                                int* __restrict__ done,
                                const float* __restrict__ Wp, const float* __restrict__ bp,
                                float* __restrict__ out) {
    int gw = (blockIdx.x * blockDim.x + threadIdx.x) >> 6;
    int lane = threadIdx.x & 63;
    const int chunk = 25;                    // 50000 / 2000 waves exact
    int start = gw * chunk;
    int end = start + chunk;
    int cur = batch[start];
    float acc = 0.f, c = 0.f;
    for (int n = start; n < end; ++n) {
        int g = batch[n];
        if (g != cur) {
            atomicAdd(&pool[cur * 64 + lane], acc);
            if (lane == 0) atomicAdd(&cnt[cur], c);
            acc = 0.f; c = 0.f; cur = g;
        }
        acc += __half2float(h[n * 64 + lane]);
        c += 1.f;
    }
    atomicAdd(&pool[cur * 64 + lane], acc);
    if (lane == 0) atomicAdd(&cnt[cur], c);
    // ---- completion detection; last block computes the head
    __syncthreads();                         // all block atomics issued & drained
    __shared__ int last;
    if (threadIdx.x == 0) last = (atomicAdd(done, 1) == (int)gridDim.x - 1);
    __syncthreads();
    if (last) {
        int f = lane;
        for (int g = (threadIdx.x >> 6); g < NGRAPH; g += 4) {
            float pv = atomicAdd(&pool[g * 64 + f], 0.0f);  // coherent read
            float v = pv * Wp[f];
#pragma unroll
            for (int off = 32; off > 0; off >>= 1) v += __shfl_down(v, off);
            if (f == 0) {
                float cv = atomicAdd(&cnt[g], 0.0f);        // coherent read
                out[g] = v / fmaxf(cv, 1.0f) + bp[0];
            }
        }
    }
}

extern "C" void kernel_launch(void* const* d_in, const int* in_sizes, int n_in,
                              void* d_out, int out_size, void* d_ws, size_t ws_size,
                              hipStream_t stream) {
    const float* x     = (const float*)d_in[0];
    const int*   ei    = (const int*)d_in[1];    // [2, E] flat: row0=src, row1=dst
    const int*   batch = (const int*)d_in[2];
    const float* W0 = (const float*)d_in[3];
    const float* b0 = (const float*)d_in[4];
    const float* W1 = (const float*)d_in[5];
    const float* b1 = (const float*)d_in[6];
    const float* W2 = (const float*)d_in[7];
    const float* b2 = (const float*)d_in[8];
    const float* Wp = (const float*)d_in[9];
    const float* bp = (const float*)d_in[10];
    float* out = (float*)d_out;

    __half* xws    = (__half*)d_ws;                    // (N+1)*64 fp16 (row N = zero sentinel)
    __half* bufH   = xws + (N_NODES + 1) * 64;         // N*64 fp16 (intermediate h)
    float* dinv    = (float*)(bufH + N_NODES * 64);    // N
    int*   row_beg = (int*)(dinv + N_NODES);           // N
    int*   row_end = row_beg + N_NODES;                // N (padded ends)
    int*   csr_src = row_end + N_NODES;                // NPART*CAP (padded layout)
    int*   bucket  = csr_src + NPART * CAP;            // NPART*CAP (padded layout)
    int*   pcount  = bucket + NPART * CAP;             // NPART
    float* pool    = (float*)(pcount + NPART);         // 64*64
    float* cnt     = pool + 64 * 64;                   // 64
    int*   done    = (int*)(cnt + 64);                 // 1

    // ---- CSR build: fixed-capacity buckets, 4-padded rows with sentinel fill
    hipMemsetAsync(pcount, 0, NPART * sizeof(int), stream);
    bucket_kernel<<<512, 256, 0, stream>>>(ei, pcount, bucket);
    csr_kernel<<<NPART, 256, 0, stream>>>(pcount, bucket, row_beg, row_end, dinv, csr_src);
    hipMemsetAsync(xws + N_NODES * 64, 0, 64 * sizeof(__half), stream);  // sentinel row

    // ---- 3 GCN layers
    const int gather_blocks = (N_NODES * 16 + 255) / 256;  // one 16-lane group per node
    // layer 0 (fp32 input x)
    gemm64_kernel<float><<<1024, 256, 0, stream>>>(x, W0, dinv, xws);
    gather_g16_kernel<<<gather_blocks, 256, 0, stream>>>(row_beg, row_end, csr_src, dinv,
                                                         xws, b0, bufH, 1);
    // layer 1 (fp16 intermediate)
    gemm64_kernel<__half><<<1024, 256, 0, stream>>>(bufH, W1, dinv, xws);
    gather_g16_kernel<<<gather_blocks, 256, 0, stream>>>(row_beg, row_end, csr_src, dinv,
                                                         xws, b1, bufH, 1);
    // layer 2 (no relu)
    gemm64_kernel<__half><<<1024, 256, 0, stream>>>(bufH, W2, dinv, xws);
    gather_g16_kernel<<<gather_blocks, 256, 0, stream>>>(row_beg, row_end, csr_src, dinv,
                                                         xws, b2, bufH, 0);

    // ---- fused pooling + head (exactly 500 blocks; last block does the head)
    hipMemsetAsync(pool, 0, (64 * 64 + 64 + 1) * sizeof(float), stream);
    poolhead_kernel<<<500, 256, 0, stream>>>(bufH, batch, pool, cnt, done, Wp, bp, out);
}

// Round 14
// 250.134 us; speedup vs baseline: 1.0352x; 1.0352x over previous
//
#include <hip/hip_runtime.h>
#include <hip/hip_fp16.h>

#define N_NODES 50000
#define N_EDGES 1250000
#define HDIM    64
#define NGRAPH  64
#define NPART   400                        // partitions for CSR build
#define PSIZE   125                        // nodes per partition (400*125 = 50000 exact)
#define CAP     4096                       // bucket capacity per partition (mean 3125, sigma 56 -> +17 sigma)

struct alignas(8) h4 { __half2 a, b; };    // 4 fp16 features, one 8-byte load/store
struct alignas(16) h8 { __half2 a, b, c, d; };  // 8 fp16 features, one 16-byte LDS read

// fp16 dot2 with fp32 accumulate: v_dot2_f32_f16 if available, else unpack+fma
typedef _Float16 half2v __attribute__((ext_vector_type(2)));
#if __has_builtin(__builtin_amdgcn_fdot2)
__device__ inline float dot2acc(__half2 a, __half2 b, float c) {
    return __builtin_amdgcn_fdot2(__builtin_bit_cast(half2v, a),
                                  __builtin_bit_cast(half2v, b), c, false);
}
#else
__device__ inline float dot2acc(__half2 a, __half2 b, float c) {
    float2 fa = __half22float2(a), fb = __half22float2(b);
    return c + fa.x * fb.x + fa.y * fb.y;
}
#endif

// ---------------------------------------------------------------- bucket edges by partition
// fixed-capacity slots: partition p owns bucket[p*CAP .. p*CAP+CAP).
// packed entry: (src << 8) | (dst % PSIZE); src < 65536, dstLocal < 125.
__global__ void bucket_kernel(const int* __restrict__ ei, int* __restrict__ pcount,
                              int* __restrict__ bucket) {
    __shared__ int hist[NPART];
    __shared__ int sbase[NPART];
    int tid = threadIdx.x;
    for (int i = tid; i < NPART; i += 256) hist[i] = 0;
    __syncthreads();
    int chunk = (N_EDGES + gridDim.x - 1) / gridDim.x;
    int beg = blockIdx.x * chunk;
    int end = min(beg + chunk, N_EDGES);
    // phase 1: count this block's edges per partition
    for (int e = beg + tid; e < end; e += 256)
        atomicAdd(&hist[ei[N_EDGES + e] / PSIZE], 1);
    __syncthreads();
    // phase 2: reserve contiguous ranges in each partition's fixed slot
    for (int i = tid; i < NPART; i += 256) {
        sbase[i] = hist[i] ? atomicAdd(&pcount[i], hist[i]) : 0;
        hist[i] = 0;   // reuse as local offset
    }
    __syncthreads();
    // phase 3: scatter packed edges
    for (int e = beg + tid; e < end; e += 256) {
        int dst = ei[N_EDGES + e];
        int src = ei[e];
        int p = dst / PSIZE;
        int l = atomicAdd(&hist[p], 1);
        bucket[p * CAP + sbase[p] + l] = (src << 8) | (dst - p * PSIZE);
    }
}

// ---------------------------------------------------------------- per-partition deg+scan+row ranges+dinv+fill
__global__ void csr_kernel(const int* __restrict__ pcount, const int* __restrict__ bucket,
                           int* __restrict__ row_beg, int* __restrict__ row_end,
                           float* __restrict__ dinv, int* __restrict__ csr_src) {
    __shared__ int hist[256];
    __shared__ int s[256];
    __shared__ int cur[128];
    int p = blockIdx.x;
    int tid = threadIdx.x;
    int base = p * CAP;
    int cnt = min(pcount[p], CAP);
    hist[tid] = 0;
    __syncthreads();
    // phase 1: degree histogram of this partition
    for (int e = tid; e < cnt; e += 256)
        atomicAdd(&hist[bucket[base + e] & 0xFF], 1);
    __syncthreads();
    int v = (tid < PSIZE) ? hist[tid] : 0;
    s[tid] = v;
    __syncthreads();
    // phase 2: in-LDS exclusive scan
    for (int off = 1; off < 256; off <<= 1) {
        int t = (tid >= off) ? s[tid - off] : 0;
        __syncthreads();
        s[tid] += t;
        __syncthreads();
    }
    if (tid < PSIZE) {
        int ex = s[tid] - v;
        int node = p * PSIZE + tid;
        row_beg[node] = base + ex;
        row_end[node] = base + ex + v;
        dinv[node] = rsqrtf((float)v + 1.0f);   // +1 self-loop
        cur[tid] = ex;
    }
    __syncthreads();
    // phase 3: fill csr_src (partition-local LDS cursors, no global atomics)
    for (int e = tid; e < cnt; e += 256) {
        int pk = bucket[base + e];
        int l = atomicAdd(&cur[pk & 0xFF], 1);
        csr_src[base + l] = pk >> 8;
    }
}

// ---------------------------------------------------------------- GEMM 64x64 -> fp16, row-scaled by dinv
// xws[n][j] = dinv[n] * sum_k h[n][k] * W[k][j];  fp16 LDS tile + dot2 inner loop.
// W held per-lane as 32 half2 registers (loaded straight from L2; no W LDS stage).
__device__ inline __half2 stage2(const float* p, int i) {
    float2 v = ((const float2*)p)[i];
    return __floats2half2_rn(v.x, v.y);
}
__device__ inline __half2 stage2(const __half* p, int i) {
    return ((const __half2*)p)[i];
}

template <typename T>
__global__ void gemm64_kernel(const T* __restrict__ h, const float* __restrict__ W,
                              const float* __restrict__ dinv, __half* __restrict__ out) {
    __shared__ alignas(16) __half2 hs2[256];   // 8 rows x 32 half2 (fp16 tile)
    int tid = threadIdx.x;
    int tx = tid & 63;       // output column (lane)
    int r0 = (tid >> 6) * 2; // this wave's two rows within the 8-row chunk
    __half2 wcol2[32];       // W[:, tx] as fp16 pairs
#pragma unroll
    for (int k2 = 0; k2 < 32; ++k2)
        wcol2[k2] = __floats2half2_rn(W[(2 * k2) * 64 + tx], W[(2 * k2 + 1) * 64 + tx]);
    const int nchunks = N_NODES / 8;  // 6250, exact
    for (int grp = blockIdx.x; grp < nchunks; grp += gridDim.x) {
        __syncthreads();                       // protect hs2 from previous iter
        hs2[tid] = stage2(h + grp * 512, tid); // 8 rows of h -> fp16 LDS
        __syncthreads();
        float acc0 = 0.f, acc1 = 0.f;
        const h8* row0 = (const h8*)&hs2[r0 * 32];
        const h8* row1 = (const h8*)&hs2[(r0 + 1) * 32];
#pragma unroll
        for (int j = 0; j < 8; ++j) {          // 8 features per b128 LDS read
            h8 v0 = row0[j];
            h8 v1 = row1[j];
            acc0 = dot2acc(v0.a, wcol2[4 * j + 0], acc0);
            acc0 = dot2acc(v0.b, wcol2[4 * j + 1], acc0);
            acc0 = dot2acc(v0.c, wcol2[4 * j + 2], acc0);
            acc0 = dot2acc(v0.d, wcol2[4 * j + 3], acc0);
            acc1 = dot2acc(v1.a, wcol2[4 * j + 0], acc1);
            acc1 = dot2acc(v1.b, wcol2[4 * j + 1], acc1);
            acc1 = dot2acc(v1.c, wcol2[4 * j + 2], acc1);
            acc1 = dot2acc(v1.d, wcol2[4 * j + 3], acc1);
        }
        int nbase = grp * 8 + r0;
        out[nbase * 64 + tx]       = __float2half(acc0 * dinv[nbase]);
        out[(nbase + 1) * 64 + tx] = __float2half(acc1 * dinv[nbase + 1]);
    }
}

// ---------------------------------------------------------------- fused gather (one 16-lane group per node)
// group = node; 16 lanes cover all 64 features (4 per lane, 8 B loads).
// out[n] = fp16( dinv[n] * (sum_e xws[src_e] + xws[n]) + b );  relu opt.
__global__ void gather_g16_kernel(const int* __restrict__ row_beg, const int* __restrict__ row_end,
                                  const int* __restrict__ csr_src,
                                  const float* __restrict__ dinv, const __half* __restrict__ xws,
                                  const float* __restrict__ b, __half* __restrict__ out,
                                  int do_relu) {
    int tid = blockIdx.x * blockDim.x + threadIdx.x;
    int node = tid >> 4;         // one 16-lane group per node
    if (node >= N_NODES) return;
    int l4 = tid & 15;           // feature quad: features 4*l4 .. 4*l4+3
    int beg = row_beg[node];
    int end = row_end[node];
    float ax = 0.f, ay = 0.f, az = 0.f, aw = 0.f;
    int e = beg;
    for (; e + 3 < end; e += 4) {          // 4 independent row loads in flight
        int s0 = csr_src[e + 0];
        int s1 = csr_src[e + 1];
        int s2 = csr_src[e + 2];
        int s3 = csr_src[e + 3];
        h4 v0 = *(const h4*)(xws + s0 * 64 + 4 * l4);
        h4 v1 = *(const h4*)(xws + s1 * 64 + 4 * l4);
        h4 v2 = *(const h4*)(xws + s2 * 64 + 4 * l4);
        h4 v3 = *(const h4*)(xws + s3 * 64 + 4 * l4);
        float2 f0a = __half22float2(v0.a), f0b = __half22float2(v0.b);
        float2 f1a = __half22float2(v1.a), f1b = __half22float2(v1.b);
        float2 f2a = __half22float2(v2.a), f2b = __half22float2(v2.b);
        float2 f3a = __half22float2(v3.a), f3b = __half22float2(v3.b);
        ax += f0a.x + f1a.x + f2a.x + f3a.x;
        ay += f0a.y + f1a.y + f2a.y + f3a.y;
        az += f0b.x + f1b.x + f2b.x + f3b.x;
        aw += f0b.y + f1b.y + f2b.y + f3b.y;
    }
    for (; e < end; ++e) {                 // tail: single edges
        int s = csr_src[e];
        h4 v = *(const h4*)(xws + s * 64 + 4 * l4);
        float2 fa = __half22float2(v.a), fb = __half22float2(v.b);
        ax += fa.x; ay += fa.y; az += fb.x; aw += fb.y;
    }
    // epilogue (once per node, no shuffles needed)
    float d = dinv[node];
    h4 sv = *(const h4*)(xws + node * 64 + 4 * l4);
    float2 sa = __half22float2(sv.a), sb = __half22float2(sv.b);
    const float4 bb = *(const float4*)(b + 4 * l4);
    float vx = d * (ax + sa.x) + bb.x;
    float vy = d * (ay + sa.y) + bb.y;
    float vz = d * (az + sb.x) + bb.z;
    float vw = d * (aw + sb.y) + bb.w;
    if (do_relu) {
        vx = fmaxf(vx, 0.f); vy = fmaxf(vy, 0.f);
        vz = fmaxf(vz, 0.f); vw = fmaxf(vw, 0.f);
    }
    h4 o;
    o.a = __float22half2_rn(make_float2(vx, vy));
    o.b = __float22half2_rn(make_float2(vz, vw));
    *(h4*)(out + node * 64 + 4 * l4) = o;
}

// ---------------------------------------------------------------- pooling (fp16 input)
// batch is sorted: each wave owns a contiguous node chunk, accumulates in a
// register per lane, flushes on graph change (few global atomics total).
__global__ void pool_kernel(const __half* __restrict__ h, const int* __restrict__ batch,
                            float* __restrict__ pool, float* __restrict__ cnt) {
    int gw = (blockIdx.x * blockDim.x + threadIdx.x) >> 6;
    int lane = threadIdx.x & 63;
    int nw = (gridDim.x * blockDim.x) >> 6;
    int chunk = (N_NODES + nw - 1) / nw;
    int start = gw * chunk;
    if (start >= N_NODES) return;
    int end = min(start + chunk, N_NODES);
    int cur = batch[start];
    float acc = 0.f, c = 0.f;
    for (int n = start; n < end; ++n) {
        int g = batch[n];
        if (g != cur) {
            atomicAdd(&pool[cur * 64 + lane], acc);
            if (lane == 0) atomicAdd(&cnt[cur], c);
            acc = 0.f; c = 0.f; cur = g;
        }
        acc += __half2float(h[n * 64 + lane]);
        c += 1.f;
    }
    atomicAdd(&pool[cur * 64 + lane], acc);
    if (lane == 0) atomicAdd(&cnt[cur], c);
}

// ---------------------------------------------------------------- head
__global__ void head_kernel(const float* __restrict__ pool, const float* __restrict__ cnt,
                            const float* __restrict__ Wp, const float* __restrict__ bp,
                            float* __restrict__ out) {
    int g = blockIdx.x;
    int k = threadIdx.x;
    float v = pool[g * 64 + k] * Wp[k];
#pragma unroll
    for (int off = 32; off > 0; off >>= 1) v += __shfl_down(v, off);
    if (k == 0) out[g] = v / fmaxf(cnt[g], 1.0f) + bp[0];
}

extern "C" void kernel_launch(void* const* d_in, const int* in_sizes, int n_in,
                              void* d_out, int out_size, void* d_ws, size_t ws_size,
                              hipStream_t stream) {
    const float* x     = (const float*)d_in[0];
    const int*   ei    = (const int*)d_in[1];    // [2, E] flat: row0=src, row1=dst
    const int*   batch = (const int*)d_in[2];
    const float* W0 = (const float*)d_in[3];
    const float* b0 = (const float*)d_in[4];
    const float* W1 = (const float*)d_in[5];
    const float* b1 = (const float*)d_in[6];
    const float* W2 = (const float*)d_in[7];
    const float* b2 = (const float*)d_in[8];
    const float* Wp = (const float*)d_in[9];
    const float* bp = (const float*)d_in[10];
    float* out = (float*)d_out;

    __half* xws    = (__half*)d_ws;                    // N*64 fp16 (dinv-scaled h@W)
    __half* bufH   = xws + N_NODES * 64;               // N*64 fp16 (intermediate h)
    float* dinv    = (float*)(bufH + N_NODES * 64);    // N
    int*   row_beg = (int*)(dinv + N_NODES);           // N
    int*   row_end = row_beg + N_NODES;                // N
    int*   csr_src = row_end + N_NODES;                // NPART*CAP (padded layout)
    int*   bucket  = csr_src + NPART * CAP;            // NPART*CAP (padded layout)
    int*   pcount  = bucket + NPART * CAP;             // NPART
    float* pool    = (float*)(pcount + NPART);         // 64*64
    float* cnt     = pool + 64 * 64;                   // 64

    // ---- CSR build: fixed-capacity buckets (no scan pass, no global atomics in fill)
    hipMemsetAsync(pcount, 0, NPART * sizeof(int), stream);
    bucket_kernel<<<512, 256, 0, stream>>>(ei, pcount, bucket);
    csr_kernel<<<NPART, 256, 0, stream>>>(pcount, bucket, row_beg, row_end, dinv, csr_src);

    // ---- 3 GCN layers
    const int gather_blocks = (N_NODES * 16 + 255) / 256;  // one 16-lane group per node
    // layer 0 (fp32 input x)
    gemm64_kernel<float><<<1024, 256, 0, stream>>>(x, W0, dinv, xws);
    gather_g16_kernel<<<gather_blocks, 256, 0, stream>>>(row_beg, row_end, csr_src, dinv,
                                                         xws, b0, bufH, 1);
    // layer 1 (fp16 intermediate)
    gemm64_kernel<__half><<<1024, 256, 0, stream>>>(bufH, W1, dinv, xws);
    gather_g16_kernel<<<gather_blocks, 256, 0, stream>>>(row_beg, row_end, csr_src, dinv,
                                                         xws, b1, bufH, 1);
    // layer 2 (no relu)
    gemm64_kernel<__half><<<1024, 256, 0, stream>>>(bufH, W2, dinv, xws);
    gather_g16_kernel<<<gather_blocks, 256, 0, stream>>>(row_beg, row_end, csr_src, dinv,
                                                         xws, b2, bufH, 0);

    // ---- pooling + head (512-block register-accumulate pool, tiny atomic flush)
    hipMemsetAsync(pool, 0, (64 * 64 + 64) * sizeof(float), stream);
    pool_kernel<<<512, 256, 0, stream>>>(bufH, batch, pool, cnt);
    head_kernel<<<64, 64, 0, stream>>>(pool, cnt, Wp, bp, out);
}